// Round 3
// baseline (454.234 us; speedup 1.0000x reference)
//
#include <hip/hip_runtime.h>
#include <math.h>

#define NPTS 65536  // N per batch (fixed by problem)

__device__ __forceinline__ float lrelu(float x) {
  // leaky_relu(x, 0.2) == 0.6*x + 0.4*|x| ; ~1e-7 rel err, 2 VALU ops
  return fmaf(0.4f, fabsf(x), 0.6f * x);
}

// x1 = leaky(features @ w_init^T + b_init) : (BN,64) -> (BN,16)
// Weights read via thread-uniform addresses -> scalar loads (no LDS).
// Also builds the padded float4 point table pts4[p] = (x,y,z,0).
__global__ __launch_bounds__(256) void k_init(
    const float* __restrict__ feats, const float* __restrict__ w,
    const float* __restrict__ bia, float* __restrict__ x1,
    const float* __restrict__ pts, float4* __restrict__ pts4, int BN) {
  int p = blockIdx.x * 256 + threadIdx.x;
  if (p >= BN) return;
  const float* pp = pts + (size_t)p * 3;
  pts4[p] = make_float4(pp[0], pp[1], pp[2], 0.0f);
  // preload feature row into registers
  float x[64];
  const float4* xr4 = (const float4*)(feats + (size_t)p * 64);
#pragma unroll
  for (int q = 0; q < 16; ++q) {
    float4 v = xr4[q];
    x[q * 4 + 0] = v.x; x[q * 4 + 1] = v.y; x[q * 4 + 2] = v.z; x[q * 4 + 3] = v.w;
  }
  float4* op = (float4*)(x1 + (size_t)p * 16);
#pragma unroll
  for (int o4 = 0; o4 < 4; ++o4) {
    float s[4];
#pragma unroll
    for (int u = 0; u < 4; ++u) {
      int o = o4 * 4 + u;
      float acc = bia[o];                    // uniform -> scalar load
      const float* wrow = w + o * 64;        // contiguous row -> s_load_dwordx16
#pragma unroll
      for (int i = 0; i < 64; ++i) acc = fmaf(x[i], wrow[i], acc);
      s[u] = lrelu(acc);
    }
    op[o4] = make_float4(s[0], s[1], s[2], s[3]);
  }
}

// LFA, 4 threads per point, split by OUTPUT CHANNEL (no cross-lane reduce):
// lane sub owns MLP outputs [sub*CMLP/4, ...) and feat channels [sub*CIN/4, ...).
// out[p] = [ mean_k leaky(geo @ w^T + b) , mean_k fin[idx[p,k]] ]
template <int CIN, int CMLP>
__global__ __launch_bounds__(256) void k_lfa(
    const float4* __restrict__ pts4, const float* __restrict__ fin,
    const int* __restrict__ idx, const float* __restrict__ w,
    const float* __restrict__ bia, float* __restrict__ out, int BN) {
  constexpr int CM4 = CMLP / 4;  // mlp outputs per sub-lane (4 or 8)
  constexpr int CF = CIN / 4;    // feat channels per sub-lane (4 or 8 floats)
  int t = threadIdx.x;
  int p = blockIdx.x * 64 + (t >> 2);
  int sub = t & 3;
  if (p >= BN) return;
  int base = p & ~(NPTS - 1);  // b*N
  float4 mp = pts4[p];
  // this lane's slice of the 4-wide MLP weights + bias, in registers
  float4 wreg[CM4];
  float breg[CM4];
  const float4* wrow = (const float4*)w + sub * CM4;
#pragma unroll
  for (int o = 0; o < CM4; ++o) {
    wreg[o] = wrow[o];
    breg[o] = bia[sub * CM4 + o];
  }
  float macc[CM4], facc[CF];
#pragma unroll
  for (int o = 0; o < CM4; ++o) macc[o] = 0.f;
#pragma unroll
  for (int c = 0; c < CF; ++c) facc[c] = 0.f;
  const int4* iv4 = (const int4*)(idx + (size_t)p * 32);
#pragma unroll 2
  for (int kk = 0; kk < 8; ++kk) {
    int4 iv = iv4[kk];
    int js[4] = {iv.x, iv.y, iv.z, iv.w};
#pragma unroll
    for (int u = 0; u < 4; ++u) {
      int j = base + js[u];
      float4 pj = pts4[j];
      float rx = mp.x - pj.x, ry = mp.y - pj.y, rz = mp.z - pj.z;
      float d = sqrtf(fmaf(rx, rx, fmaf(ry, ry, rz * rz)));
#pragma unroll
      for (int o = 0; o < CM4; ++o) {
        float4 wv = wreg[o];
        float s = fmaf(rx, wv.x, fmaf(ry, wv.y, fmaf(rz, wv.z, fmaf(d, wv.w, breg[o]))));
        macc[o] += lrelu(s);
      }
      // group-coalesced: 4 sub-lanes cover the neighbor's full row
      const float4* fj = (const float4*)(fin + (size_t)j * CIN) + sub * (CF / 4);
#pragma unroll
      for (int c4 = 0; c4 < CF / 4; ++c4) {
        float4 fv = fj[c4];
        facc[c4 * 4 + 0] += fv.x;
        facc[c4 * 4 + 1] += fv.y;
        facc[c4 * 4 + 2] += fv.z;
        facc[c4 * 4 + 3] += fv.w;
      }
    }
  }
  const float inv = 1.0f / 32.0f;
  float* orow = out + (size_t)p * (CMLP + CIN);
  float* om = orow + sub * CM4;
#pragma unroll
  for (int q = 0; q < CM4 / 4; ++q) {
    ((float4*)om)[q] = make_float4(macc[q * 4 + 0] * inv, macc[q * 4 + 1] * inv,
                                   macc[q * 4 + 2] * inv, macc[q * 4 + 3] * inv);
  }
  float* of = orow + CMLP + sub * CF;
#pragma unroll
  for (int q = 0; q < CF / 4; ++q) {
    ((float4*)of)[q] = make_float4(facc[q * 4 + 0] * inv, facc[q * 4 + 1] * inv,
                                   facc[q * 4 + 2] * inv, facc[q * 4 + 3] * inv);
  }
}

// out = leaky(x3 @ wf^T + bf) + leaky(feats @ wr^T + br)   (in-place safe on x3==out)
// Weights via thread-uniform global reads -> scalar loads; no LDS at all.
__global__ __launch_bounds__(256) void k_final(
    const float* __restrict__ x3, const float* __restrict__ feats,
    const float* __restrict__ wf, const float* __restrict__ bf,
    const float* __restrict__ wr, const float* __restrict__ brs,
    float* __restrict__ out, int BN) {
  int p = blockIdx.x * 256 + threadIdx.x;
  if (p >= BN) return;
  float x[64];
  // ---- pass 1: y = leaky(x3 @ wf^T + bf), kept in registers ----
  const float4* xr4 = (const float4*)(x3 + (size_t)p * 64);
#pragma unroll
  for (int q = 0; q < 16; ++q) {
    float4 v = xr4[q];
    x[q * 4 + 0] = v.x; x[q * 4 + 1] = v.y; x[q * 4 + 2] = v.z; x[q * 4 + 3] = v.w;
  }
  float y[64];
#pragma unroll 16
  for (int o = 0; o < 64; ++o) {
    float acc = bf[o];                     // uniform -> scalar
    const float* wrow = wf + o * 64;       // contiguous -> s_load_dwordx16
#pragma unroll
    for (int i = 0; i < 64; ++i) acc = fmaf(x[i], wrow[i], acc);
    y[o] = lrelu(acc);
  }
  // ---- pass 2: out = y + leaky(feats @ wr^T + br) ----
  const float4* fr4 = (const float4*)(feats + (size_t)p * 64);
#pragma unroll
  for (int q = 0; q < 16; ++q) {
    float4 v = fr4[q];
    x[q * 4 + 0] = v.x; x[q * 4 + 1] = v.y; x[q * 4 + 2] = v.z; x[q * 4 + 3] = v.w;
  }
  float4* op = (float4*)(out + (size_t)p * 64);
#pragma unroll
  for (int o4 = 0; o4 < 16; ++o4) {
    float s[4];
#pragma unroll
    for (int u = 0; u < 4; ++u) {
      int o = o4 * 4 + u;
      float acc = brs[o];
      const float* wrow = wr + o * 64;
#pragma unroll
      for (int i = 0; i < 64; ++i) acc = fmaf(x[i], wrow[i], acc);
      s[u] = y[o] + lrelu(acc);
    }
    op[o4] = make_float4(s[0], s[1], s[2], s[3]);
  }
}

extern "C" void kernel_launch(void* const* d_in, const int* in_sizes, int n_in,
                              void* d_out, int out_size, void* d_ws, size_t ws_size,
                              hipStream_t stream) {
  const float* pts    = (const float*)d_in[0];
  const float* feats  = (const float*)d_in[1];
  const int*   idx    = (const int*)d_in[2];
  const float* w_init = (const float*)d_in[3];
  const float* b_init = (const float*)d_in[4];
  const float* w_l1   = (const float*)d_in[5];
  const float* b_l1   = (const float*)d_in[6];
  const float* w_l2   = (const float*)d_in[7];
  const float* b_l2   = (const float*)d_in[8];
  const float* w_f    = (const float*)d_in[9];
  const float* b_f    = (const float*)d_in[10];
  const float* w_r    = (const float*)d_in[11];
  const float* b_r    = (const float*)d_in[12];
  float* out = (float*)d_out;

  int BN = in_sizes[2] / 32;  // B*N = 131072
  // ws layout: x2 (BN*32 f32 = 16 MB) | pts4 (BN*16B = 2 MB).  x1 lives in d_out.
  float* x2 = (float*)d_ws;
  float4* pts4 = (float4*)((char*)d_ws + (size_t)BN * 32 * sizeof(float));
  float* x1 = out;  // 8 MB of the 32 MB output buffer; dead before x3 is written

  int blocks_pt = (BN + 255) / 256;   // thread-per-point kernels
  int blocks_g = (BN + 63) / 64;      // 4-threads-per-point gather kernels

  k_init<<<blocks_pt, 256, 0, stream>>>(feats, w_init, b_init, x1, pts, pts4, BN);
  k_lfa<16, 16><<<blocks_g, 256, 0, stream>>>(pts4, x1, idx, w_l1, b_l1, x2, BN);
  k_lfa<32, 32><<<blocks_g, 256, 0, stream>>>(pts4, x2, idx, w_l2, b_l2, out, BN);
  k_final<<<blocks_pt, 256, 0, stream>>>(out, feats, w_f, b_f, w_r, b_r, out, BN);
}

// Round 4
// 297.908 us; speedup vs baseline: 1.5247x; 1.5247x over previous
//
#include <hip/hip_runtime.h>
#include <math.h>

#define NPTS 65536  // N per batch (fixed by problem)

typedef __attribute__((ext_vector_type(8))) short bf16x8;
typedef __attribute__((ext_vector_type(4))) float f32x4;

__device__ __forceinline__ float lrelu(float x) {
  // leaky_relu(x, 0.2) == 0.6*x + 0.4*|x| ; ~1e-7 rel err, 2 VALU ops
  return fmaf(0.4f, fabsf(x), 0.6f * x);
}

// pack 8 consecutive f32 -> 8 bf16 (RNE), via two float4 vector loads
__device__ __forceinline__ bf16x8 cvt8(const float* p) {
  float4 a = ((const float4*)p)[0];
  float4 b = ((const float4*)p)[1];
  float f[8] = {a.x, a.y, a.z, a.w, b.x, b.y, b.z, b.w};
  bf16x8 r;
#pragma unroll
  for (int j = 0; j < 8; ++j) {
    union { float f; unsigned u; } v;
    v.f = f[j];
    unsigned u = v.u + (0x7fffu + ((v.u >> 16) & 1u));  // round-nearest-even
    r[j] = (short)(u >> 16);
  }
  return r;
}

// x1 = leaky(features @ w_init^T + b_init) : (BN,64) -> (BN,16)  [R2-proven LDS version]
// also builds the padded float4 point table pts4[p] = (x,y,z,0)
__global__ __launch_bounds__(256) void k_init(
    const float* __restrict__ feats, const float* __restrict__ w,
    const float* __restrict__ bia, float* __restrict__ x1,
    const float* __restrict__ pts, float4* __restrict__ pts4, int BN) {
  __shared__ float wt[64 * 16];  // wt[i*16+o] = w[o*64+i]
  int t = threadIdx.x;
  for (int e = t; e < 1024; e += 256) {
    int o = e >> 6, i = e & 63;
    wt[i * 16 + o] = w[e];
  }
  __syncthreads();
  int p = blockIdx.x * 256 + t;
  if (p >= BN) return;
  const float* pp = pts + (size_t)p * 3;
  pts4[p] = make_float4(pp[0], pp[1], pp[2], 0.0f);
  float acc[16];
#pragma unroll
  for (int o = 0; o < 16; ++o) acc[o] = bia[o];
  const float* xr = feats + (size_t)p * 64;
#pragma unroll 8
  for (int i = 0; i < 64; ++i) {
    float xi = xr[i];
    const float4* w4 = (const float4*)&wt[i * 16];
#pragma unroll
    for (int q = 0; q < 4; ++q) {
      float4 wv = w4[q];
      acc[q * 4 + 0] = fmaf(xi, wv.x, acc[q * 4 + 0]);
      acc[q * 4 + 1] = fmaf(xi, wv.y, acc[q * 4 + 1]);
      acc[q * 4 + 2] = fmaf(xi, wv.z, acc[q * 4 + 2]);
      acc[q * 4 + 3] = fmaf(xi, wv.w, acc[q * 4 + 3]);
    }
  }
  float4* op = (float4*)(x1 + (size_t)p * 16);
#pragma unroll
  for (int q = 0; q < 4; ++q) {
    float4 v;
    v.x = lrelu(acc[q * 4 + 0]);
    v.y = lrelu(acc[q * 4 + 1]);
    v.z = lrelu(acc[q * 4 + 2]);
    v.w = lrelu(acc[q * 4 + 3]);
    op[q] = v;
  }
}

// LFA, 4 threads per point, split by OUTPUT CHANNEL (no cross-lane reduce)
template <int CIN, int CMLP>
__global__ __launch_bounds__(256) void k_lfa(
    const float4* __restrict__ pts4, const float* __restrict__ fin,
    const int* __restrict__ idx, const float* __restrict__ w,
    const float* __restrict__ bia, float* __restrict__ out, int BN) {
  constexpr int CM4 = CMLP / 4;
  constexpr int CF = CIN / 4;
  int t = threadIdx.x;
  int p = blockIdx.x * 64 + (t >> 2);
  int sub = t & 3;
  if (p >= BN) return;
  int base = p & ~(NPTS - 1);  // b*N
  float4 mp = pts4[p];
  float4 wreg[CM4];
  float breg[CM4];
  const float4* wrow = (const float4*)w + sub * CM4;
#pragma unroll
  for (int o = 0; o < CM4; ++o) {
    wreg[o] = wrow[o];
    breg[o] = bia[sub * CM4 + o];
  }
  float macc[CM4], facc[CF];
#pragma unroll
  for (int o = 0; o < CM4; ++o) macc[o] = 0.f;
#pragma unroll
  for (int c = 0; c < CF; ++c) facc[c] = 0.f;
  const int4* iv4 = (const int4*)(idx + (size_t)p * 32);
#pragma unroll 2
  for (int kk = 0; kk < 8; ++kk) {
    int4 iv = iv4[kk];
    int js[4] = {iv.x, iv.y, iv.z, iv.w};
#pragma unroll
    for (int u = 0; u < 4; ++u) {
      int j = base + js[u];
      float4 pj = pts4[j];
      float rx = mp.x - pj.x, ry = mp.y - pj.y, rz = mp.z - pj.z;
      float d = sqrtf(fmaf(rx, rx, fmaf(ry, ry, rz * rz)));
#pragma unroll
      for (int o = 0; o < CM4; ++o) {
        float4 wv = wreg[o];
        float s = fmaf(rx, wv.x, fmaf(ry, wv.y, fmaf(rz, wv.z, fmaf(d, wv.w, breg[o]))));
        macc[o] += lrelu(s);
      }
      const float4* fj = (const float4*)(fin + (size_t)j * CIN) + sub * (CF / 4);
#pragma unroll
      for (int c4 = 0; c4 < CF / 4; ++c4) {
        float4 fv = fj[c4];
        facc[c4 * 4 + 0] += fv.x;
        facc[c4 * 4 + 1] += fv.y;
        facc[c4 * 4 + 2] += fv.z;
        facc[c4 * 4 + 3] += fv.w;
      }
    }
  }
  const float inv = 1.0f / 32.0f;
  float* orow = out + (size_t)p * (CMLP + CIN);
  float* om = orow + sub * CM4;
#pragma unroll
  for (int q = 0; q < CM4 / 4; ++q) {
    ((float4*)om)[q] = make_float4(macc[q * 4 + 0] * inv, macc[q * 4 + 1] * inv,
                                   macc[q * 4 + 2] * inv, macc[q * 4 + 3] * inv);
  }
  float* of = orow + CMLP + sub * CF;
#pragma unroll
  for (int q = 0; q < CF / 4; ++q) {
    ((float4*)of)[q] = make_float4(facc[q * 4 + 0] * inv, facc[q * 4 + 1] * inv,
                                   facc[q * 4 + 2] * inv, facc[q * 4 + 3] * inv);
  }
}

// out = leaky(x3 @ wf^T + bf) + leaky(feats @ wr^T + br), via bf16 MFMA.
// One wave = 16 rows x 64 cols, K=64 in two 16x16x32 chunks per col-tile.
// In-place safe (x3 == out): A-frags are in registers before any store.
__global__ __launch_bounds__(256) void k_final(
    const float* __restrict__ x3, const float* __restrict__ feats,
    const float* __restrict__ wf, const float* __restrict__ bfi,
    const float* __restrict__ wr, const float* __restrict__ bri,
    float* __restrict__ out, int BN) {
  int lane = threadIdx.x & 63;
  int wave = threadIdx.x >> 6;
  int quad = lane >> 4, n = lane & 15;
  size_t rowbase = ((size_t)blockIdx.x * 4 + wave) * 16;
  // B-frags: B[k][col] = W[col][k]; lane holds W[nt*16+n][c*32+quad*8 .. +8]
  bf16x8 Bf[4][2], Br[4][2];
#pragma unroll
  for (int nt = 0; nt < 4; ++nt)
#pragma unroll
    for (int c = 0; c < 2; ++c) {
      int off = (nt * 16 + n) * 64 + c * 32 + quad * 8;
      Bf[nt][c] = cvt8(wf + off);
      Br[nt][c] = cvt8(wr + off);
    }
  // A-frags: lane holds row rowbase+n, k = c*32+quad*8 .. +8
  const float* ax = x3 + (rowbase + n) * 64 + quad * 8;
  bf16x8 Ax0 = cvt8(ax), Ax1 = cvt8(ax + 32);
  const float* af = feats + (rowbase + n) * 64 + quad * 8;
  bf16x8 Af0 = cvt8(af), Af1 = cvt8(af + 32);
  // pass 1: y = leaky(x3 @ wf^T + bf)
  float y[16];
#pragma unroll
  for (int nt = 0; nt < 4; ++nt) {
    f32x4 acc = {0.f, 0.f, 0.f, 0.f};
    acc = __builtin_amdgcn_mfma_f32_16x16x32_bf16(Ax0, Bf[nt][0], acc, 0, 0, 0);
    acc = __builtin_amdgcn_mfma_f32_16x16x32_bf16(Ax1, Bf[nt][1], acc, 0, 0, 0);
    float bias = bfi[nt * 16 + n];
#pragma unroll
    for (int r = 0; r < 4; ++r) y[nt * 4 + r] = lrelu(acc[r] + bias);
  }
  // pass 2: out = y + leaky(feats @ wr^T + br)
#pragma unroll
  for (int nt = 0; nt < 4; ++nt) {
    f32x4 acc = {0.f, 0.f, 0.f, 0.f};
    acc = __builtin_amdgcn_mfma_f32_16x16x32_bf16(Af0, Br[nt][0], acc, 0, 0, 0);
    acc = __builtin_amdgcn_mfma_f32_16x16x32_bf16(Af1, Br[nt][1], acc, 0, 0, 0);
    float bias = bri[nt * 16 + n];
#pragma unroll
    for (int r = 0; r < 4; ++r) {
      // C/D: col = lane&15 (+nt*16), row = quad*4 + r
      size_t row = rowbase + quad * 4 + r;
      out[row * 64 + nt * 16 + n] = y[nt * 4 + r] + lrelu(acc[r] + bias);
    }
  }
}

extern "C" void kernel_launch(void* const* d_in, const int* in_sizes, int n_in,
                              void* d_out, int out_size, void* d_ws, size_t ws_size,
                              hipStream_t stream) {
  const float* pts    = (const float*)d_in[0];
  const float* feats  = (const float*)d_in[1];
  const int*   idx    = (const int*)d_in[2];
  const float* w_init = (const float*)d_in[3];
  const float* b_init = (const float*)d_in[4];
  const float* w_l1   = (const float*)d_in[5];
  const float* b_l1   = (const float*)d_in[6];
  const float* w_l2   = (const float*)d_in[7];
  const float* b_l2   = (const float*)d_in[8];
  const float* w_f    = (const float*)d_in[9];
  const float* b_f    = (const float*)d_in[10];
  const float* w_r    = (const float*)d_in[11];
  const float* b_r    = (const float*)d_in[12];
  float* out = (float*)d_out;

  int BN = in_sizes[2] / 32;  // B*N = 131072
  // ws layout: x2 (BN*32 f32 = 16 MB) | pts4 (BN*16B = 2 MB).  x1 lives in d_out.
  float* x2 = (float*)d_ws;
  float4* pts4 = (float4*)((char*)d_ws + (size_t)BN * 32 * sizeof(float));
  float* x1 = out;  // 8 MB of the 32 MB output buffer; dead before x3 is written

  int blocks_pt = (BN + 255) / 256;   // thread-per-point kernels
  int blocks_g = (BN + 63) / 64;      // 4-threads-per-point gather kernels
  int blocks_mf = (BN + 63) / 64;     // MFMA kernel: 64 rows per 256-thr block

  k_init<<<blocks_pt, 256, 0, stream>>>(feats, w_init, b_init, x1, pts, pts4, BN);
  k_lfa<16, 16><<<blocks_g, 256, 0, stream>>>(pts4, x1, idx, w_l1, b_l1, x2, BN);
  k_lfa<32, 32><<<blocks_g, 256, 0, stream>>>(pts4, x2, idx, w_l2, b_l2, out, BN);
  k_final<<<blocks_mf, 256, 0, stream>>>(out, feats, w_f, b_f, w_r, b_r, out, BN);
}

// Round 5
// 283.609 us; speedup vs baseline: 1.6016x; 1.0504x over previous
//
#include <hip/hip_runtime.h>
#include <math.h>

#define NPTS 65536  // N per batch (fixed by problem)

typedef unsigned short ushort_t;
typedef unsigned int uint_t;
typedef __attribute__((ext_vector_type(8))) short bf16x8;
typedef __attribute__((ext_vector_type(4))) float f32x4;

__device__ __forceinline__ float lrelu(float x) {
  return fmaf(0.4f, fabsf(x), 0.6f * x);  // leaky_relu(x,0.2)
}
__device__ __forceinline__ ushort_t f2b(float f) {  // f32->bf16 RNE
  union { float f; uint_t u; } v; v.f = f;
  uint_t u = v.u + (0x7fffu + ((v.u >> 16) & 1u));
  return (ushort_t)(u >> 16);
}
__device__ __forceinline__ float b2f_lo(uint_t u) {
  union { uint_t u; float f; } v; v.u = u << 16; return v.f;
}
__device__ __forceinline__ float b2f_hi(uint_t u) {
  union { uint_t u; float f; } v; v.u = u & 0xffff0000u; return v.f;
}
// pack 8 consecutive f32 -> 8 bf16 (RNE)
__device__ __forceinline__ bf16x8 cvt8(const float* p) {
  float4 a = ((const float4*)p)[0];
  float4 b = ((const float4*)p)[1];
  float f[8] = {a.x, a.y, a.z, a.w, b.x, b.y, b.z, b.w};
  bf16x8 r;
#pragma unroll
  for (int j = 0; j < 8; ++j) r[j] = (short)f2b(f[j]);
  return r;
}

// x1 = leaky(features @ w_init^T + b_init) -> bf16 (BN,16); also builds pts4.
__global__ __launch_bounds__(256) void k_init(
    const float* __restrict__ feats, const float* __restrict__ w,
    const float* __restrict__ bia, ushort_t* __restrict__ x1,
    const float* __restrict__ pts, float4* __restrict__ pts4, int BN) {
  __shared__ float wt[64 * 16];  // wt[i*16+o] = w[o*64+i]
  int t = threadIdx.x;
  for (int e = t; e < 1024; e += 256) {
    int o = e >> 6, i = e & 63;
    wt[i * 16 + o] = w[e];
  }
  __syncthreads();
  int p = blockIdx.x * 256 + t;
  if (p >= BN) return;
  const float* pp = pts + (size_t)p * 3;
  pts4[p] = make_float4(pp[0], pp[1], pp[2], 0.0f);
  float acc[16];
#pragma unroll
  for (int o = 0; o < 16; ++o) acc[o] = bia[o];
  const float* xr = feats + (size_t)p * 64;
#pragma unroll 8
  for (int i = 0; i < 64; ++i) {
    float xi = xr[i];
    const float4* w4 = (const float4*)&wt[i * 16];
#pragma unroll
    for (int q = 0; q < 4; ++q) {
      float4 wv = w4[q];
      acc[q * 4 + 0] = fmaf(xi, wv.x, acc[q * 4 + 0]);
      acc[q * 4 + 1] = fmaf(xi, wv.y, acc[q * 4 + 1]);
      acc[q * 4 + 2] = fmaf(xi, wv.z, acc[q * 4 + 2]);
      acc[q * 4 + 3] = fmaf(xi, wv.w, acc[q * 4 + 3]);
    }
  }
  union { ushort_t u[16]; uint4 v[2]; } pk;
#pragma unroll
  for (int o = 0; o < 16; ++o) pk.u[o] = f2b(lrelu(acc[o]));
  uint4* op = (uint4*)(x1 + (size_t)p * 16);
  op[0] = pk.v[0];
  op[1] = pk.v[1];
}

// LFA1: x1 bf16 (BN,16) -> x2 bf16 (BN,32). 4 lanes/point, channel-split.
__global__ __launch_bounds__(256) void k_lfa1(
    const float4* __restrict__ pts4, const ushort_t* __restrict__ fin,
    const int* __restrict__ idx, const float* __restrict__ w,
    const float* __restrict__ bia, ushort_t* __restrict__ out, int BN) {
  int t = threadIdx.x;
  int p = blockIdx.x * 64 + (t >> 2);
  int sub = t & 3;
  if (p >= BN) return;
  int base = p & ~(NPTS - 1);
  float4 mp = pts4[p];
  float4 wreg[4];
  float breg[4];
  const float4* wrow = (const float4*)w + sub * 4;
#pragma unroll
  for (int o = 0; o < 4; ++o) { wreg[o] = wrow[o]; breg[o] = bia[sub * 4 + o]; }
  float macc[4] = {0.f, 0.f, 0.f, 0.f};
  float facc[4] = {0.f, 0.f, 0.f, 0.f};
  const int4* iv4 = (const int4*)(idx + (size_t)p * 32);
#pragma unroll 2
  for (int kk = 0; kk < 8; ++kk) {
    int4 iv = iv4[kk];
    int js[4] = {iv.x, iv.y, iv.z, iv.w};
#pragma unroll
    for (int u = 0; u < 4; ++u) {
      int j = base + js[u];
      float4 pj = pts4[j];
      float rx = mp.x - pj.x, ry = mp.y - pj.y, rz = mp.z - pj.z;
      float d = sqrtf(fmaf(rx, rx, fmaf(ry, ry, rz * rz)));
#pragma unroll
      for (int o = 0; o < 4; ++o) {
        float4 wv = wreg[o];
        float s = fmaf(rx, wv.x, fmaf(ry, wv.y, fmaf(rz, wv.z, fmaf(d, wv.w, breg[o]))));
        macc[o] += lrelu(s);
      }
      uint2 fv = *((const uint2*)(fin + (size_t)j * 16) + sub);  // 4 bf16
      facc[0] += b2f_lo(fv.x); facc[1] += b2f_hi(fv.x);
      facc[2] += b2f_lo(fv.y); facc[3] += b2f_hi(fv.y);
    }
  }
  const float inv = 1.0f / 32.0f;
  ushort_t* orow = out + (size_t)p * 32;
  union { ushort_t u[4]; uint2 v; } pm, pf;
#pragma unroll
  for (int q = 0; q < 4; ++q) {
    pm.u[q] = f2b(macc[q] * inv);
    pf.u[q] = f2b(facc[q] * inv);
  }
  ((uint2*)orow)[sub] = pm.v;       // MLP section [0,16)
  ((uint2*)orow)[4 + sub] = pf.v;   // feat section [16,32)
}

// LFA2: x2 bf16 (BN,32) -> x3 f32 (BN,64) in d_out. 4 lanes/point.
__global__ __launch_bounds__(256) void k_lfa2(
    const float4* __restrict__ pts4, const ushort_t* __restrict__ fin,
    const int* __restrict__ idx, const float* __restrict__ w,
    const float* __restrict__ bia, float* __restrict__ out, int BN) {
  int t = threadIdx.x;
  int p = blockIdx.x * 64 + (t >> 2);
  int sub = t & 3;
  if (p >= BN) return;
  int base = p & ~(NPTS - 1);
  float4 mp = pts4[p];
  float4 wreg[8];
  float breg[8];
  const float4* wrow = (const float4*)w + sub * 8;
#pragma unroll
  for (int o = 0; o < 8; ++o) { wreg[o] = wrow[o]; breg[o] = bia[sub * 8 + o]; }
  float macc[8], facc[8];
#pragma unroll
  for (int o = 0; o < 8; ++o) { macc[o] = 0.f; facc[o] = 0.f; }
  const int4* iv4 = (const int4*)(idx + (size_t)p * 32);
#pragma unroll 2
  for (int kk = 0; kk < 8; ++kk) {
    int4 iv = iv4[kk];
    int js[4] = {iv.x, iv.y, iv.z, iv.w};
#pragma unroll
    for (int u = 0; u < 4; ++u) {
      int j = base + js[u];
      float4 pj = pts4[j];
      float rx = mp.x - pj.x, ry = mp.y - pj.y, rz = mp.z - pj.z;
      float d = sqrtf(fmaf(rx, rx, fmaf(ry, ry, rz * rz)));
#pragma unroll
      for (int o = 0; o < 8; ++o) {
        float4 wv = wreg[o];
        float s = fmaf(rx, wv.x, fmaf(ry, wv.y, fmaf(rz, wv.z, fmaf(d, wv.w, breg[o]))));
        macc[o] += lrelu(s);
      }
      uint4 fv = *((const uint4*)(fin + (size_t)j * 32) + sub);  // 8 bf16
      facc[0] += b2f_lo(fv.x); facc[1] += b2f_hi(fv.x);
      facc[2] += b2f_lo(fv.y); facc[3] += b2f_hi(fv.y);
      facc[4] += b2f_lo(fv.z); facc[5] += b2f_hi(fv.z);
      facc[6] += b2f_lo(fv.w); facc[7] += b2f_hi(fv.w);
    }
  }
  const float inv = 1.0f / 32.0f;
  float* orow = out + (size_t)p * 64;
  float4* om = (float4*)orow + sub * 2;        // MLP [0,32)
  om[0] = make_float4(macc[0] * inv, macc[1] * inv, macc[2] * inv, macc[3] * inv);
  om[1] = make_float4(macc[4] * inv, macc[5] * inv, macc[6] * inv, macc[7] * inv);
  float4* of = (float4*)orow + 8 + sub * 2;    // feat [32,64)
  of[0] = make_float4(facc[0] * inv, facc[1] * inv, facc[2] * inv, facc[3] * inv);
  of[1] = make_float4(facc[4] * inv, facc[5] * inv, facc[6] * inv, facc[7] * inv);
}

// out = leaky(x3 @ wf^T + bf) + leaky(feats @ wr^T + br), bf16 MFMA.
// One wave = 16 rows x 64 cols; in-place safe (A-frags in regs before stores).
__global__ __launch_bounds__(256) void k_final(
    const float* __restrict__ x3, const float* __restrict__ feats,
    const float* __restrict__ wf, const float* __restrict__ bfi,
    const float* __restrict__ wr, const float* __restrict__ bri,
    float* __restrict__ out, int BN) {
  int lane = threadIdx.x & 63;
  int wave = threadIdx.x >> 6;
  int quad = lane >> 4, n = lane & 15;
  size_t rowbase = ((size_t)blockIdx.x * 4 + wave) * 16;
  bf16x8 Bf[4][2], Br[4][2];
#pragma unroll
  for (int nt = 0; nt < 4; ++nt)
#pragma unroll
    for (int c = 0; c < 2; ++c) {
      int off = (nt * 16 + n) * 64 + c * 32 + quad * 8;
      Bf[nt][c] = cvt8(wf + off);
      Br[nt][c] = cvt8(wr + off);
    }
  const float* ax = x3 + (rowbase + n) * 64 + quad * 8;
  bf16x8 Ax0 = cvt8(ax), Ax1 = cvt8(ax + 32);
  const float* af = feats + (rowbase + n) * 64 + quad * 8;
  bf16x8 Af0 = cvt8(af), Af1 = cvt8(af + 32);
  float y[16];
#pragma unroll
  for (int nt = 0; nt < 4; ++nt) {
    f32x4 acc = {0.f, 0.f, 0.f, 0.f};
    acc = __builtin_amdgcn_mfma_f32_16x16x32_bf16(Ax0, Bf[nt][0], acc, 0, 0, 0);
    acc = __builtin_amdgcn_mfma_f32_16x16x32_bf16(Ax1, Bf[nt][1], acc, 0, 0, 0);
    float bias = bfi[nt * 16 + n];
#pragma unroll
    for (int r = 0; r < 4; ++r) y[nt * 4 + r] = lrelu(acc[r] + bias);
  }
#pragma unroll
  for (int nt = 0; nt < 4; ++nt) {
    f32x4 acc = {0.f, 0.f, 0.f, 0.f};
    acc = __builtin_amdgcn_mfma_f32_16x16x32_bf16(Af0, Br[nt][0], acc, 0, 0, 0);
    acc = __builtin_amdgcn_mfma_f32_16x16x32_bf16(Af1, Br[nt][1], acc, 0, 0, 0);
    float bias = bri[nt * 16 + n];
#pragma unroll
    for (int r = 0; r < 4; ++r) {
      size_t row = rowbase + quad * 4 + r;  // C/D: col=lane&15, row=quad*4+r
      out[row * 64 + nt * 16 + n] = y[nt * 4 + r] + lrelu(acc[r] + bias);
    }
  }
}

extern "C" void kernel_launch(void* const* d_in, const int* in_sizes, int n_in,
                              void* d_out, int out_size, void* d_ws, size_t ws_size,
                              hipStream_t stream) {
  const float* pts    = (const float*)d_in[0];
  const float* feats  = (const float*)d_in[1];
  const int*   idx    = (const int*)d_in[2];
  const float* w_init = (const float*)d_in[3];
  const float* b_init = (const float*)d_in[4];
  const float* w_l1   = (const float*)d_in[5];
  const float* b_l1   = (const float*)d_in[6];
  const float* w_l2   = (const float*)d_in[7];
  const float* b_l2   = (const float*)d_in[8];
  const float* w_f    = (const float*)d_in[9];
  const float* b_f    = (const float*)d_in[10];
  const float* w_r    = (const float*)d_in[11];
  const float* b_r    = (const float*)d_in[12];
  float* out = (float*)d_out;

  int BN = in_sizes[2] / 32;  // B*N = 131072
  // ws: x1 bf16 (4 MB) | x2 bf16 (8 MB) | pts4 (2 MB) = 14 MB
  ushort_t* x1 = (ushort_t*)d_ws;
  ushort_t* x2 = x1 + (size_t)BN * 16;
  float4* pts4 = (float4*)(x2 + (size_t)BN * 32);

  int blocks_pt = (BN + 255) / 256;
  int blocks_g = (BN + 63) / 64;

  k_init<<<blocks_pt, 256, 0, stream>>>(feats, w_init, b_init, x1, pts, pts4, BN);
  k_lfa1<<<blocks_g, 256, 0, stream>>>(pts4, x1, idx, w_l1, b_l1, x2, BN);
  k_lfa2<<<blocks_g, 256, 0, stream>>>(pts4, x2, idx, w_l2, b_l2, out, BN);
  k_final<<<blocks_g, 256, 0, stream>>>(out, feats, w_f, b_f, w_r, b_r, out, BN);
}